// Round 1
// baseline (74.813 us; speedup 1.0000x reference)
//
#include <hip/hip_runtime.h>

// And_Convolution: out[n,w] = min_{j=0..15}( input[n, 4*w + j] * weight[j] )
// N=1024, L=8192, KERNEL=16, STRIDE=4 -> NWIN = (8192-16)/4 + 1 = 2045.
//
// STRIDE==4 means window w is exactly float4 chunks [w, w+3] of the row:
// one thread per output window, 4 coalesced float4 loads, fminf tree.
// Memory-bound: ~42 MB total traffic -> ~6.6 us HBM floor.

#define KER 16
#define STR 4
#define ROWLEN 8192
#define NWIN 2045  // (ROWLEN - KER) / STR + 1

__global__ __launch_bounds__(256) void and_conv_kernel(
    const float* __restrict__ inp,
    const float* __restrict__ wgt,
    float* __restrict__ out) {
    const int w = blockIdx.x * 256 + threadIdx.x;
    const int n = blockIdx.y;
    if (w >= NWIN) return;

    const float4* row = (const float4*)(inp + (size_t)n * ROWLEN);
    // Window w spans float4 chunks w..w+3 (all in-bounds for w <= 2044).
    float4 c0 = row[w];
    float4 c1 = row[w + 1];
    float4 c2 = row[w + 2];
    float4 c3 = row[w + 3];

    // Weights: wave-uniform address -> compiler emits scalar loads.
    const float4* wv = (const float4*)wgt;
    float4 w0 = wv[0];
    float4 w1 = wv[1];
    float4 w2 = wv[2];
    float4 w3 = wv[3];

    float m0 = fminf(fminf(c0.x * w0.x, c0.y * w0.y),
                     fminf(c0.z * w0.z, c0.w * w0.w));
    float m1 = fminf(fminf(c1.x * w1.x, c1.y * w1.y),
                     fminf(c1.z * w1.z, c1.w * w1.w));
    float m2 = fminf(fminf(c2.x * w2.x, c2.y * w2.y),
                     fminf(c2.z * w2.z, c2.w * w2.w));
    float m3 = fminf(fminf(c3.x * w3.x, c3.y * w3.y),
                     fminf(c3.z * w3.z, c3.w * w3.w));

    out[(size_t)n * NWIN + w] = fminf(fminf(m0, m1), fminf(m2, m3));
}

extern "C" void kernel_launch(void* const* d_in, const int* in_sizes, int n_in,
                              void* d_out, int out_size, void* d_ws, size_t ws_size,
                              hipStream_t stream) {
    const float* inp = (const float*)d_in[0];
    const float* wgt = (const float*)d_in[1];
    float* out = (float*)d_out;

    const int N = in_sizes[0] / ROWLEN;  // 1024
    dim3 grid((NWIN + 255) / 256, N);    // 8 x 1024 blocks
    and_conv_kernel<<<grid, dim3(256), 0, stream>>>(inp, wgt, out);
}